// Round 3
// baseline (332.021 us; speedup 1.0000x reference)
//
#include <hip/hip_runtime.h>

typedef unsigned short u16;
typedef unsigned int u32;
typedef __attribute__((ext_vector_type(4))) float f32x4;
typedef __attribute__((ext_vector_type(8))) short s16x8;
typedef __attribute__((ext_vector_type(4))) u16 u16x4;

#define L2E 1.4426950408889634f
#define QSCALE 0.18033688011112042f /* (1/8) * log2(e) */

__device__ __forceinline__ u16 f2bf(float f) {  // RNE
    union { float f; u32 i; } v; v.f = f;
    return (u16)((v.i + 0x7fffu + ((v.i >> 16) & 1u)) >> 16);
}
__device__ __forceinline__ u16 f2bf_rn(float f) {
    union { float f; u32 i; } v; v.f = f;
    return (u16)((v.i + 0x8000u) >> 16);
}

// ---------------------------------------------------------------------------
// Convert the 6 big fp32 tensors (Qin, KVin, Wq, Wk, Wv, Wo) to bf16 in ws.
// ---------------------------------------------------------------------------
__global__ __launch_bounds__(256) void conv_kernel(
    const float* __restrict__ s0, const float* __restrict__ s1,
    const float* __restrict__ s2, const float* __restrict__ s3,
    const float* __restrict__ s4, const float* __restrict__ s5,
    u16* __restrict__ dst)
{
    int e = (blockIdx.x * 256 + threadIdx.x) * 4;
    const float* src; int off;
    if      (e < 4194304) { src = s0; off = e; }
    else if (e < 8388608) { src = s1; off = e - 4194304; }
    else if (e < 8650752) { src = s2; off = e - 8388608; }
    else if (e < 8912896) { src = s3; off = e - 8650752; }
    else if (e < 9175040) { src = s4; off = e - 8912896; }
    else                  { src = s5; off = e - 9175040; }
    f32x4 f = *(const f32x4*)(src + off);
    u16x4 o;
#pragma unroll
    for (int j = 0; j < 4; ++j) o[j] = f2bf(f[j]);
    *(u16x4*)(dst + e) = o;
}

// ---------------------------------------------------------------------------
// GEMM core: C[128x128] = A[128x512] * B^T, bf16 operands, K-major rows.
// ---------------------------------------------------------------------------
__device__ __forceinline__ void gemm_core(
    const u16* __restrict__ A, const u16* __restrict__ Bw,
    int m0, int n0, u16* As, u16* Bs, f32x4 acc[4][4])
{
    const int tid = threadIdx.x;
    const int lane = tid & 63, w = tid >> 6;
    const int wm = w >> 1, wn = w & 1;
    const int l16 = lane & 15, quad = lane >> 4;
    const f32x4 vzero = {0.f, 0.f, 0.f, 0.f};
#pragma unroll
    for (int i = 0; i < 4; ++i)
#pragma unroll
        for (int j = 0; j < 4; ++j) acc[i][j] = vzero;

    for (int kt = 0; kt < 16; ++kt) {
#pragma unroll
        for (int r = 0; r < 2; ++r) {
            int seg = r * 256 + tid;
            int row = seg >> 2, ch = seg & 3;
            *(uint4*)&As[row * 40 + ch * 8] =
                *(const uint4*)&A[(size_t)(m0 + row) * 512 + kt * 32 + ch * 8];
            *(uint4*)&Bs[row * 40 + ch * 8] =
                *(const uint4*)&Bw[(size_t)(n0 + row) * 512 + kt * 32 + ch * 8];
        }
        __syncthreads();
        s16x8 af[4], bfr[4];
#pragma unroll
        for (int mt = 0; mt < 4; ++mt)
            af[mt] = *(const s16x8*)&As[(wm * 64 + mt * 16 + l16) * 40 + quad * 8];
#pragma unroll
        for (int nt = 0; nt < 4; ++nt)
            bfr[nt] = *(const s16x8*)&Bs[(wn * 64 + nt * 16 + l16) * 40 + quad * 8];
#pragma unroll
        for (int mt = 0; mt < 4; ++mt)
#pragma unroll
            for (int nt = 0; nt < 4; ++nt)
                acc[mt][nt] = __builtin_amdgcn_mfma_f32_16x16x32_bf16(
                    af[mt], bfr[nt], acc[mt][nt], 0, 0, 0);
        __syncthreads();
    }
}

// ---------------------------------------------------------------------------
// QKV projection. job 0=Q (scaled, ->[B,H,N,64]), 1=K, 2=V (-> [B,H,64,N]).
// ---------------------------------------------------------------------------
__global__ __launch_bounds__(256) void proj_kernel(
    const u16* __restrict__ cQin, const u16* __restrict__ cKV,
    const u16* __restrict__ cW,  /* Wq|Wk|Wv|Wo flat bf16 */
    const float* __restrict__ bq, const float* __restrict__ bk,
    const float* __restrict__ bv,
    u16* __restrict__ Qh, u16* __restrict__ Kh, u16* __restrict__ Vt)
{
    __shared__ __align__(16) u16 As[128 * 40];
    __shared__ __align__(16) u16 Bs[128 * 40];
    const int job = blockIdx.z;
    const u16* A = (job == 0) ? cQin : cKV;
    const u16* W = cW + (size_t)job * 262144;
    const float* bias = (job == 0) ? bq : (job == 1 ? bk : bv);
    const int m0 = blockIdx.y * 128, n0 = blockIdx.x * 128;
    f32x4 acc[4][4];
    gemm_core(A, W, m0, n0, As, Bs, acc);

    const int tid = threadIdx.x, lane = tid & 63, w = tid >> 6;
    const int wm = w >> 1, wn = w & 1, l16 = lane & 15, quad = lane >> 4;
#pragma unroll
    for (int nt = 0; nt < 4; ++nt) {
        int j = n0 + wn * 64 + nt * 16 + l16;
        float bj = bias[j];
        int h = j >> 6, d = j & 63;
#pragma unroll
        for (int mt = 0; mt < 4; ++mt) {
            int trow = m0 + wm * 64 + mt * 16 + quad * 4;
            int bb = trow >> 11, nn = trow & 2047;
            int bh = bb * 8 + h;
            if (job == 2) {
                u16x4 pv;
#pragma unroll
                for (int reg = 0; reg < 4; ++reg) pv[reg] = f2bf(acc[mt][nt][reg] + bj);
                *(u16x4*)&Vt[(size_t)(bh * 64 + d) * 2048 + nn] = pv;
            } else if (job == 0) {
#pragma unroll
                for (int reg = 0; reg < 4; ++reg)
                    Qh[(size_t)(bh * 2048 + nn + reg) * 64 + d] =
                        f2bf((acc[mt][nt][reg] + bj) * QSCALE);
            } else {
#pragma unroll
                for (int reg = 0; reg < 4; ++reg)
                    Kh[(size_t)(bh * 2048 + nn + reg) * 64 + d] =
                        f2bf(acc[mt][nt][reg] + bj);
            }
        }
    }
}

// ---------------------------------------------------------------------------
// Attention. Block = (32 q-rows, 1 batch), 8 waves = 8 heads. Gate tile
// computed once per SC element into shared LDS (reused by all 8 heads).
// ---------------------------------------------------------------------------
__global__ __launch_bounds__(512) void attn_kernel(
    const u16* __restrict__ Qh, const u16* __restrict__ Kh,
    const u16* __restrict__ Vt, const float* __restrict__ SC,
    const float* __restrict__ gwp, const float* __restrict__ gbp,
    u16* __restrict__ Ob)
{
    __shared__ __align__(16) u16 Plds[8][32][72];
    __shared__ __align__(16) float LgL[32][68];
    const int tid = threadIdx.x;
    const int h = tid >> 6, lane = tid & 63;
    const int l16 = lane & 15, quad = lane >> 4;
    const int b = blockIdx.y, q0 = blockIdx.x * 32;
    const int bh = b * 8 + h;
    const float gw = gwp[0], gb = gbp[0];
    const u16* Qp = Qh + (size_t)bh * 2048 * 64;
    const u16* Kp = Kh + (size_t)bh * 2048 * 64;
    const u16* Vp = Vt + (size_t)bh * 64 * 2048;
    const f32x4 vzero = {0.f, 0.f, 0.f, 0.f};

    s16x8 qf[2][2];
#pragma unroll
    for (int qm = 0; qm < 2; ++qm)
#pragma unroll
        for (int kc = 0; kc < 2; ++kc)
            qf[qm][kc] = *(const s16x8*)&Qp[(size_t)(q0 + qm * 16 + l16) * 64 +
                                            kc * 32 + quad * 8];
    f32x4 o[2][4], lsum[2];
#pragma unroll
    for (int qm = 0; qm < 2; ++qm) {
        lsum[qm] = vzero;
#pragma unroll
        for (int dn = 0; dn < 4; ++dn) o[qm][dn] = vzero;
    }

    const int eA = tid * 4, qrA = eA >> 6, kcA = eA & 63;
    const float* scp = SC + (size_t)b * 2048 * 2048 + (size_t)(q0 + qrA) * 2048 + kcA;

    for (int kt = 0; kt < 32; ++kt) {
        const int k0 = kt * 64;
        // Phase A: gate tile lg[32][64] cooperatively (512 thr x 4 elems)
        f32x4 t = *(const f32x4*)(scp + k0);
        f32x4 lg4;
#pragma unroll
        for (int j = 0; j < 4; ++j) {
            float u = gw * t[j] + gb;
            float ee = __builtin_amdgcn_exp2f(-u * L2E);
            float sg = __builtin_amdgcn_rcpf(1.0f + ee);
            lg4[j] = __builtin_amdgcn_logf(sg + 1e-8f);  // v_log_f32 = log2
        }
        *(f32x4*)&LgL[qrA][kcA] = lg4;
        __syncthreads();

        // Phase B: QK^T -> gate+exp2 -> P -> PV (per-wave, wave-private Plds)
        f32x4 s[2][4];
#pragma unroll
        for (int qm = 0; qm < 2; ++qm)
#pragma unroll
            for (int kn = 0; kn < 4; ++kn) s[qm][kn] = vzero;
#pragma unroll
        for (int kc = 0; kc < 2; ++kc) {
            s16x8 kf[4];
#pragma unroll
            for (int kn = 0; kn < 4; ++kn)
                kf[kn] = *(const s16x8*)&Kp[(size_t)(k0 + kn * 16 + l16) * 64 +
                                            kc * 32 + quad * 8];
#pragma unroll
            for (int qm = 0; qm < 2; ++qm)
#pragma unroll
                for (int kn = 0; kn < 4; ++kn)
                    s[qm][kn] = __builtin_amdgcn_mfma_f32_16x16x32_bf16(
                        qf[qm][kc], kf[kn], s[qm][kn], 0, 0, 0);
        }
#pragma unroll
        for (int qm = 0; qm < 2; ++qm)
#pragma unroll
            for (int kn = 0; kn < 4; ++kn)
#pragma unroll
                for (int reg = 0; reg < 4; ++reg) {
                    float lg = LgL[qm * 16 + quad * 4 + reg][kn * 16 + l16];
                    float p = __builtin_amdgcn_exp2f(s[qm][kn][reg] + lg);
                    lsum[qm][reg] += p;
                    Plds[h][qm * 16 + quad * 4 + reg][kn * 16 + l16] = f2bf_rn(p);
                }
#pragma unroll
        for (int kc = 0; kc < 2; ++kc) {
            s16x8 vf[4];
#pragma unroll
            for (int dn = 0; dn < 4; ++dn)
                vf[dn] = *(const s16x8*)&Vp[(size_t)(dn * 16 + l16) * 2048 +
                                            k0 + kc * 32 + quad * 8];
#pragma unroll
            for (int qm = 0; qm < 2; ++qm) {
                s16x8 pf = *(const s16x8*)&Plds[h][qm * 16 + l16][kc * 32 + quad * 8];
#pragma unroll
                for (int dn = 0; dn < 4; ++dn)
                    o[qm][dn] = __builtin_amdgcn_mfma_f32_16x16x32_bf16(
                        pf, vf[dn], o[qm][dn], 0, 0, 0);
            }
        }
        __syncthreads();  // protect LgL before next Phase A
    }
#pragma unroll
    for (int qm = 0; qm < 2; ++qm)
#pragma unroll
        for (int reg = 0; reg < 4; ++reg) {
            float l = lsum[qm][reg];
            l += __shfl_xor(l, 1, 64);
            l += __shfl_xor(l, 2, 64);
            l += __shfl_xor(l, 4, 64);
            l += __shfl_xor(l, 8, 64);
            float inv = __builtin_amdgcn_rcpf(l);
            int trow = b * 2048 + q0 + qm * 16 + quad * 4 + reg;
#pragma unroll
            for (int dn = 0; dn < 4; ++dn)
                Ob[(size_t)trow * 512 + h * 64 + dn * 16 + l16] =
                    f2bf(o[qm][dn][reg] * inv);
        }
}

// ---------------------------------------------------------------------------
// Output projection: out = Ob @ Wo^T + bo, fp32 out (reference output dtype).
// ---------------------------------------------------------------------------
__global__ __launch_bounds__(256) void out_kernel(
    const u16* __restrict__ Ob, const u16* __restrict__ cWo,
    const float* __restrict__ bo, float* __restrict__ out)
{
    __shared__ __align__(16) u16 As[128 * 40];
    __shared__ __align__(16) u16 Bs[128 * 40];
    const int m0 = blockIdx.y * 128, n0 = blockIdx.x * 128;
    f32x4 acc[4][4];
    gemm_core(Ob, cWo, m0, n0, As, Bs, acc);
    const int tid = threadIdx.x, lane = tid & 63, w = tid >> 6;
    const int wm = w >> 1, wn = w & 1, l16 = lane & 15, quad = lane >> 4;
#pragma unroll
    for (int nt = 0; nt < 4; ++nt) {
        int j = n0 + wn * 64 + nt * 16 + l16;
        float bj = bo[j];
#pragma unroll
        for (int mt = 0; mt < 4; ++mt) {
            int t = m0 + wm * 64 + mt * 16 + quad * 4;
#pragma unroll
            for (int reg = 0; reg < 4; ++reg)
                out[(size_t)(t + reg) * 512 + j] = acc[mt][nt][reg] + bj;
        }
    }
}

extern "C" void kernel_launch(void* const* d_in, const int* in_sizes, int n_in,
                              void* d_out, int out_size, void* d_ws, size_t ws_size,
                              hipStream_t stream)
{
    const float* Qin  = (const float*)d_in[0];
    const float* KVin = (const float*)d_in[1];
    const float* SC   = (const float*)d_in[2];
    const float* Wq   = (const float*)d_in[3];
    const float* bq   = (const float*)d_in[4];
    const float* Wk   = (const float*)d_in[5];
    const float* bk   = (const float*)d_in[6];
    const float* Wv   = (const float*)d_in[7];
    const float* bv   = (const float*)d_in[8];
    const float* gw   = (const float*)d_in[9];
    const float* gb   = (const float*)d_in[10];
    const float* Wo   = (const float*)d_in[11];
    const float* bo   = (const float*)d_in[12];
    float* out = (float*)d_out;

    // ws layout (u16 units), 50 MiB total
    u16* conv = (u16*)d_ws;            // 9,437,184: cQin|cKV|cWq|cWk|cWv|cWo
    u16* cQin = conv;
    u16* cKV  = conv + 4194304;
    u16* cW   = conv + 8388608;        // Wq,Wk,Wv,Wo each 262,144
    u16* Qh   = conv + 9437184;        // each 4,194,304
    u16* Kh   = Qh + 4194304;
    u16* Vt   = Kh + 4194304;
    u16* Ob   = Vt + 4194304;

    hipLaunchKernelGGL(conv_kernel, dim3(9216), dim3(256), 0, stream,
                       Qin, KVin, Wq, Wk, Wv, Wo, conv);
    hipLaunchKernelGGL(proj_kernel, dim3(4, 64, 3), dim3(256), 0, stream,
                       cQin, cKV, cW, bq, bk, bv, Qh, Kh, Vt);
    hipLaunchKernelGGL(attn_kernel, dim3(64, 4), dim3(512), 0, stream,
                       Qh, Kh, Vt, SC, gw, gb, Ob);
    hipLaunchKernelGGL(out_kernel, dim3(4, 64), dim3(256), 0, stream,
                       Ob, cW + 786432, bo, out);
}